// Round 14
// baseline (58.880 us; speedup 1.0000x reference)
//
#include <hip/hip_runtime.h>
#include <hip/hip_bf16.h>
#include <float.h>

#define NHEAD 8

typedef __attribute__((ext_vector_type(8))) short bf16x8;
typedef __attribute__((ext_vector_type(4))) float f32x4;

static __device__ __forceinline__ unsigned short bfb(float f) {
    __hip_bfloat16 h = __float2bfloat16(f);
    unsigned short u; __builtin_memcpy(&u, &h, 2); return u;
}
static __device__ __forceinline__ unsigned int pk2(float a, float b) {
    return (unsigned int)bfb(a) | ((unsigned int)bfb(b) << 16);
}
static __device__ __forceinline__ float bf2f_lo(unsigned int u) { return __uint_as_float(u << 16); }
static __device__ __forceinline__ float bf2f_hi(unsigned int u) { return __uint_as_float(u & 0xffff0000u); }

// sK [384][64] / sRW [256][64]: u16, XOR-8 row swizzle
static __device__ __forceinline__ int swz64(int r, int c) {
    return (r << 6) + (c ^ ((r & 7) << 3));
}
// sV: [64 c][384 kk] u16; chunk-XOR within each 128-kk block
static __device__ __forceinline__ int vIdx(int c, int kk) {
    const int blk = kk >> 7, k7 = kk & 127;
    const int ch  = ((k7 >> 3) ^ (c & 15));
    return c * 384 + blk * 128 + ch * 8 + (kk & 7);
}
// sP: per-wave [16][40] u16 slab, 16B-chunk XOR; col in [0,32)
static __device__ __forceinline__ int pIdx(int wv, int row, int col) {
    const int ch = (col >> 3) ^ (row & 3);
    return (wv * 16 + row) * 40 + ch * 8 + (col & 7);
}

static __device__ __forceinline__ f32x4 mfma16(bf16x8 a, bf16x8 b, f32x4 c) {
    return __builtin_amdgcn_mfma_f32_16x16x32_bf16(a, b, c, 0, 0, 0);
}

__global__ __launch_bounds__(1024, 1)
void local_attn_kernel(const float* __restrict__ qg, const float* __restrict__ kg,
                       const float* __restrict__ vg, const float* __restrict__ rwg,
                       float* __restrict__ outg)
{
    __shared__ __align__(16) unsigned short sK[384 * 64];      // 48 KB: K_norm (384-row window)
    __shared__ __align__(16) unsigned short sV[64 * 384];      // 48 KB: V^T
    __shared__ __align__(16) unsigned short sRW[256 * 64];     // 32 KB: rel-weights
    __shared__ __align__(16) unsigned short sP[16 * 16 * 40];  // 20 KB: per-wave P slabs

    const int tid  = threadIdx.x;
    const int lane = tid & 63;
    const int wv   = tid >> 6;       // 0..15
    const int wvL  = wv & 7;
    const int bkt  = wv >> 3;        // 0 = bucket nb, 1 = bucket nb+1
    const int jl   = lane & 15;
    const int hi   = lane >> 4;      // 0..3

    // XCD-bijective swizzle: 512 blocks = 8 XCDs x 64
    const int lb = ((blockIdx.x & 7) << 6) + (blockIdx.x >> 3);
    const int bh = lb >> 5;          // 0..15
    const int nb = (lb & 31) << 1;   // even bucket; block covers nb, nb+1
    const int h  = bh & 7;

    const float scale = 0.125f;
    const size_t bhOff = (size_t)bh * 8192 * 64;
    const int n = nb + bkt;          // this wave's bucket

    // staged window: rows 0..383 = global tokens (nb-1)*128 + row
    const float* Kw = kg + bhOff + ((long)nb - 1) * 128 * 64;
    const float* Vw = vg + bhOff + ((long)nb - 1) * 128 * 64;

    const int cr6 = tid >> 4;         // 0..63
    const int c0  = (tid & 15) << 2;  // feature group of 4

    // ---- V -> sV: lane = column, 24 kk rows per wave-group, pack + 3x b128 ----
    {
        const int vc = tid & 63;
        const int vg0 = (tid >> 6) * 24;  // kk base for this group
        unsigned int vp[12];
        #pragma unroll
        for (int u = 0; u < 12; ++u) {
            const int k0 = vg0 + 2 * u;
            float a = 0.f, b = 0.f;
            if (!(nb == 0 && k0 < 128))       a = Vw[(size_t)k0 * 64 + vc];
            if (!(nb == 0 && (k0 + 1) < 128)) b = Vw[(size_t)(k0 + 1) * 64 + vc];
            vp[u] = pk2(a, b);
        }
        #pragma unroll
        for (int w4 = 0; w4 < 3; ++w4) {
            const uint4 w = make_uint4(vp[4 * w4], vp[4 * w4 + 1], vp[4 * w4 + 2], vp[4 * w4 + 3]);
            *reinterpret_cast<uint4*>(&sV[vIdx(vc, vg0 + 8 * w4)]) = w;
        }
    }

    // ---- K -> normalize (shfl over 16 lanes) -> sK (6 passes x 64 rows) ----
    #pragma unroll
    for (int pp = 0; pp < 6; ++pp) {
        const int row = pp * 64 + cr6;
        f32x4 x = {0.f, 0.f, 0.f, 0.f};
        if (!(nb == 0 && row < 128))
            x = *reinterpret_cast<const f32x4*>(Kw + (size_t)row * 64 + c0);
        float ss = x[0] * x[0] + x[1] * x[1] + x[2] * x[2] + x[3] * x[3];
        ss += __shfl_xor(ss, 1);
        ss += __shfl_xor(ss, 2);
        ss += __shfl_xor(ss, 4);
        ss += __shfl_xor(ss, 8);
        const float rn = 1.0f / fmaxf(sqrtf(ss), 1e-12f);
        ushort4 pkk = make_ushort4(bfb(x[0] * rn), bfb(x[1] * rn),
                                   bfb(x[2] * rn), bfb(x[3] * rn));
        *reinterpret_cast<ushort4*>(&sK[swz64(row, c0)]) = pkk;
    }

    // ---- RW -> sRW (4 passes x 64 rows) ----
    #pragma unroll
    for (int pp = 0; pp < 4; ++pp) {
        const int row = pp * 64 + cr6;
        const f32x4 x = *reinterpret_cast<const f32x4*>(rwg + ((size_t)row * NHEAD + h) * 64 + c0);
        ushort4 pkw = make_ushort4(bfb(x[0]), bfb(x[1]), bfb(x[2]), bfb(x[3]));
        *reinterpret_cast<ushort4*>(&sRW[swz64(row, c0)]) = pkw;
    }

    // ---- Q fragments direct from global (own bucket) ----
    const int arow = wvL * 16 + jl;
    const int kq0  = hi << 3;
    const float* qr = qg + bhOff + (size_t)n * 128 * 64 + arow * 64 + kq0;
    const f32x4 qa = *reinterpret_cast<const f32x4*>(qr);
    const f32x4 qb = *reinterpret_cast<const f32x4*>(qr + 4);
    const f32x4 qc = *reinterpret_cast<const f32x4*>(qr + 32);
    const f32x4 qd = *reinterpret_cast<const f32x4*>(qr + 36);
    bf16x8 aq0, aq1;
    #pragma unroll
    for (int q = 0; q < 4; ++q) {
        aq0[q]     = (short)bfb(qa[q] * scale);
        aq0[q + 4] = (short)bfb(qb[q] * scale);
        aq1[q]     = (short)bfb(qc[q] * scale);
        aq1[q + 4] = (short)bfb(qd[q] * scale);
    }

    __syncthreads();  // B1 — the ONLY barrier

    const int tMax = wvL + 8;
    const int bOff = bkt << 7;        // K/V row offset for this bucket

    // ---- QK^T loop: pure MFMA ----
    f32x4 dots[16] = {};
    __builtin_amdgcn_s_setprio(1);
    #pragma unroll
    for (int t = 0; t < 16; ++t) {
        if (t <= tMax) {
            const int rr = bOff + t * 16 + jl;
            const bf16x8 b0 = *reinterpret_cast<const bf16x8*>(&sK[swz64(rr, kq0)]);
            const bf16x8 b1 = *reinterpret_cast<const bf16x8*>(&sK[swz64(rr, 32 + kq0)]);
            f32x4 d = {0.f, 0.f, 0.f, 0.f};
            d = mfma16(aq0, b0, d);
            d = mfma16(aq1, b1, d);
            dots[t] = d;
        }
    }
    __builtin_amdgcn_s_setprio(0);

    // ---- bias loop (rolling 2 slots on sRW) + masks + exp, in place ----
    const int cv0 = 4 * hi + 1, cv1 = 4 * hi + 2, cv2 = 4 * hi + 3, cv3 = 4 * hi + 4;
    const int sl0 = (hi << 4) | ((jl - cv0) & 15);
    const int sl1 = (hi << 4) | ((jl - cv1) & 15);
    const int sl2 = (hi << 4) | ((jl - cv2) & 15);
    const int sl3 = (hi << 4) | ((jl - cv3) & 15);
    const bool g0 = jl >= cv0, g1 = jl >= cv1, g2 = jl >= cv2, g3 = jl >= cv3;

    unsigned int cur01, cur23;
    {
        const int rr = (7 - wvL) * 16 + jl;   // slot 0 = rel-tile 7-wvL
        const bf16x8 b0 = *reinterpret_cast<const bf16x8*>(&sRW[swz64(rr, kq0)]);
        const bf16x8 b1 = *reinterpret_cast<const bf16x8*>(&sRW[swz64(rr, 32 + kq0)]);
        f32x4 e = {0.f, 0.f, 0.f, 0.f};
        e = mfma16(aq0, b0, e);
        e = mfma16(aq1, b1, e);
        cur01 = pk2(e[0], e[1]);
        cur23 = pk2(e[2], e[3]);
    }
    unsigned int lo0 = (unsigned int)__shfl((int)cur01, sl0);
    unsigned int lo1 = (unsigned int)__shfl((int)cur01, sl1);
    unsigned int lo2 = (unsigned int)__shfl((int)cur23, sl2);
    unsigned int lo3 = (unsigned int)__shfl((int)cur23, sl3);

    float sm[4] = {0.f, 0.f, 0.f, 0.f};
    const bool npad = (n == 0);

    #pragma unroll
    for (int t = 0; t < 16; ++t) {
        if (t <= tMax) {
            unsigned int n01 = 0, n23 = 0;
            const int ts = t + 8 - wvL;          // slot t+1
            if (ts < 16) {
                const int rr2 = ts * 16 + jl;
                const bf16x8 e0 = *reinterpret_cast<const bf16x8*>(&sRW[swz64(rr2, kq0)]);
                const bf16x8 e1 = *reinterpret_cast<const bf16x8*>(&sRW[swz64(rr2, 32 + kq0)]);
                f32x4 e = {0.f, 0.f, 0.f, 0.f};
                e = mfma16(aq0, e0, e);
                e = mfma16(aq1, e1, e);
                n01 = pk2(e[0], e[1]);
                n23 = pk2(e[2], e[3]);
            }
            const unsigned int h0 = (unsigned int)__shfl((int)n01, sl0);
            const unsigned int h1 = (unsigned int)__shfl((int)n01, sl1);
            const unsigned int h2 = (unsigned int)__shfl((int)n23, sl2);
            const unsigned int h3 = (unsigned int)__shfl((int)n23, sl3);
            f32x4 d = dots[t];
            d[0] += bf2f_lo(g0 ? h0 : lo0);
            d[1] += bf2f_hi(g1 ? h1 : lo1);
            d[2] += bf2f_lo(g2 ? h2 : lo2);
            d[3] += bf2f_hi(g3 ? h3 : lo3);
            lo0 = h0; lo1 = h1; lo2 = h2; lo3 = h3;
            if (t >= 8 && t == tMax) {
                #pragma unroll
                for (int r = 0; r < 4; ++r) {
                    const int dd = 128 + jl - 4 * hi - r;
                    float x = d[r];
                    x = (dd == 128) ? -50.0f : x;   // self (exp=2e-22 keeps token-0 row alive)
                    x = (dd > 128) ? -3.0e38f : x;  // causal
                    d[r] = x;
                }
            }
            if (t < 8 && npad) {
                #pragma unroll
                for (int r = 0; r < 4; ++r) d[r] = -3.0e38f;
            }
            #pragma unroll
            for (int r = 0; r < 4; ++r) {
                const float pe = __expf(d[r]);
                d[r] = pe;
                sm[r] += pe;
            }
            dots[t] = d;
        }
    }

    float rinv[4];
    #pragma unroll
    for (int r = 0; r < 4; ++r) {
        sm[r] += __shfl_xor(sm[r], 1);
        sm[r] += __shfl_xor(sm[r], 2);
        sm[r] += __shfl_xor(sm[r], 4);
        sm[r] += __shfl_xor(sm[r], 8);
        rinv[r] = 1.0f / sm[r];
    }

    // ---- PV: per-wave P slab (wave-private, no barriers); V from sV ----
    f32x4 o[4] = {};
    #pragma unroll
    for (int pv = 0; pv < 8; ++pv) {
        if (2 * pv <= tMax) {
            #pragma unroll
            for (int tt = 0; tt < 2; ++tt) {
                const int t = 2 * pv + tt;
                unsigned int w01 = 0, w23 = 0;
                if (t <= tMax) {
                    w01 = pk2(dots[t][0], dots[t][1]);
                    w23 = pk2(dots[t][2], dots[t][3]);
                }
                const int col = tt * 16 + jl;
                sP[pIdx(wv, 4 * hi + 0, col)] = (unsigned short)w01;
                sP[pIdx(wv, 4 * hi + 1, col)] = (unsigned short)(w01 >> 16);
                sP[pIdx(wv, 4 * hi + 2, col)] = (unsigned short)w23;
                sP[pIdx(wv, 4 * hi + 3, col)] = (unsigned short)(w23 >> 16);
            }
            const bf16x8 pa = *reinterpret_cast<const bf16x8*>(&sP[pIdx(wv, jl, kq0)]);
            __builtin_amdgcn_s_setprio(1);
            #pragma unroll
            for (int ct = 0; ct < 4; ++ct) {
                const bf16x8 vb = *reinterpret_cast<const bf16x8*>(&sV[vIdx(ct * 16 + jl, bOff + pv * 32 + kq0)]);
                o[ct] = mfma16(pa, vb, o[ct]);
            }
            __builtin_amdgcn_s_setprio(0);
        }
    }

    // ---- epilogue ----
    const int ibase = wvL * 16 + (hi << 2);
    float* Op = outg + bhOff + (size_t)n * 128 * 64;
    #pragma unroll
    for (int ct = 0; ct < 4; ++ct)
        #pragma unroll
        for (int r = 0; r < 4; ++r)
            Op[(ibase + r) * 64 + ct * 16 + jl] = o[ct][r] * rinv[r];
}

extern "C" void kernel_launch(void* const* d_in, const int* in_sizes, int n_in,
                              void* d_out, int out_size, void* d_ws, size_t ws_size,
                              hipStream_t stream) {
    const float* q  = (const float*)d_in[0];
    const float* k  = (const float*)d_in[1];
    const float* v  = (const float*)d_in[2];
    const float* rw = (const float*)d_in[3];
    float* out = (float*)d_out;
    local_attn_kernel<<<dim3(512), dim3(1024), 0, stream>>>(q, k, v, rw, out);
}

// Round 15
// 48.465 us; speedup vs baseline: 1.2149x; 1.2149x over previous
//
#include <hip/hip_runtime.h>
#include <hip/hip_bf16.h>
#include <float.h>

#define NHEAD 8

typedef __attribute__((ext_vector_type(8))) short bf16x8;
typedef __attribute__((ext_vector_type(4))) float f32x4;

static __device__ __forceinline__ unsigned short bfb(float f) {
    __hip_bfloat16 h = __float2bfloat16(f);
    unsigned short u; __builtin_memcpy(&u, &h, 2); return u;
}
static __device__ __forceinline__ unsigned int pk2(float a, float b) {
    return (unsigned int)bfb(a) | ((unsigned int)bfb(b) << 16);
}
static __device__ __forceinline__ float bf2f_lo(unsigned int u) { return __uint_as_float(u << 16); }
static __device__ __forceinline__ float bf2f_hi(unsigned int u) { return __uint_as_float(u & 0xffff0000u); }

// sB (RW -> K_norm): [256][64] u16, XOR-8 swizzle
static __device__ __forceinline__ int swz64(int r, int c) {
    return (r << 6) + (c ^ ((r & 7) << 3));
}
// sV: [64 c][256 kk] u16, chunk-XOR-32 (b128 r/w at bank floor)
static __device__ __forceinline__ int vIdx(int c, int kk) {
    return (c << 8) + (kk ^ ((c & 31) << 3));
}
// sP: per-wave [16][40] u16 slab, 16B-chunk XOR; col in [0,32)
static __device__ __forceinline__ int pIdx(int wv, int row, int col) {
    const int ch = (col >> 3) ^ (row & 3);
    return (wv * 16 + row) * 40 + ch * 8 + (col & 7);
}

static __device__ __forceinline__ f32x4 mfma16(bf16x8 a, bf16x8 b, f32x4 c) {
    return __builtin_amdgcn_mfma_f32_16x16x32_bf16(a, b, c, 0, 0, 0);
}

__global__ __launch_bounds__(512, 4)
void local_attn_kernel(const float* __restrict__ qg, const float* __restrict__ kg,
                       const float* __restrict__ vg, const float* __restrict__ rwg,
                       float* __restrict__ outg)
{
    __shared__ __align__(16) unsigned short sB[256 * 64];     // 32 KB: RW -> K_norm
    __shared__ __align__(16) unsigned short sV[64 * 256];     // 32 KB: V^T
    __shared__ __align__(16) unsigned short sP[8 * 16 * 40];  // 10 KB: per-wave P slabs

    const int tid  = threadIdx.x;
    const int lane = tid & 63;
    const int wv   = tid >> 6;       // 0..7
    const int jl   = lane & 15;
    const int hi   = lane >> 4;      // 0..3

    // XCD-bijective swizzle: 1024 blocks = 8 XCDs x 128
    const int lb = ((blockIdx.x & 7) << 7) + (blockIdx.x >> 3);
    const int bh = lb >> 6;
    const int n  = lb & 63;
    const int h  = bh & 7;

    const float scale = 0.125f;
    const size_t bhOff = (size_t)bh * 8192 * 64;

    const float* Qp = qg + bhOff + (size_t)n * 128 * 64;
    const float* Kp = kg + bhOff + ((long)n - 1) * 128 * 64;
    const float* Vp = vg + bhOff + ((long)n - 1) * 128 * 64;

    const int cr = tid >> 4;          // 0..31
    const int c0 = (tid & 15) << 2;   // feature group of 4

    // ---- V -> sV directly (lane = column, pack pairwise, b128 dumps; transient) ----
    {
        const int vc  = tid & 63;
        const int vkb = (tid >> 6) << 5;          // kk = vkb..vkb+31
        const bool vzero = (n == 0 && vkb < 128); // wave-uniform
        #pragma unroll
        for (int w4 = 0; w4 < 4; ++w4) {
            unsigned int vp[4];
            #pragma unroll
            for (int u = 0; u < 4; ++u) {
                const int k0 = vkb + 8 * w4 + 2 * u;
                float a = 0.f, b = 0.f;
                if (!vzero) {
                    a = Vp[(size_t)k0 * 64 + vc];
                    b = Vp[(size_t)(k0 + 1) * 64 + vc];
                }
                vp[u] = pk2(a, b);
            }
            *reinterpret_cast<uint4*>(&sV[vIdx(vc, vkb + 8 * w4)]) =
                make_uint4(vp[0], vp[1], vp[2], vp[3]);
        }
    }

    // ---- K -> normalize -> PACKED regs kpk[8] (16 VGPRs, held until B2 dump) ----
    uint2 kpk[8];
    #pragma unroll
    for (int pp = 0; pp < 8; ++pp) {
        const int row = pp * 32 + cr;
        f32x4 x = {0.f, 0.f, 0.f, 0.f};
        if (!(n == 0 && row < 128))
            x = *reinterpret_cast<const f32x4*>(Kp + (size_t)row * 64 + c0);
        float ss = x[0] * x[0] + x[1] * x[1] + x[2] * x[2] + x[3] * x[3];
        ss += __shfl_xor(ss, 1);
        ss += __shfl_xor(ss, 2);
        ss += __shfl_xor(ss, 4);
        ss += __shfl_xor(ss, 8);
        const float rn = 1.0f / fmaxf(sqrtf(ss), 1e-12f);
        kpk[pp] = make_uint2(pk2(x[0] * rn, x[1] * rn), pk2(x[2] * rn, x[3] * rn));
    }
    #pragma unroll
    for (int pp = 0; pp < 8; ++pp)
        asm volatile("" :: "v"(kpk[pp].x), "v"(kpk[pp].y));  // keep-alive

    // ---- RW -> sB directly ----
    #pragma unroll
    for (int pp = 0; pp < 8; ++pp) {
        const int row = pp * 32 + cr;
        const f32x4 x = *reinterpret_cast<const f32x4*>(rwg + ((size_t)row * NHEAD + h) * 64 + c0);
        ushort4 pkw = make_ushort4(bfb(x[0]), bfb(x[1]), bfb(x[2]), bfb(x[3]));
        *reinterpret_cast<ushort4*>(&sB[swz64(row, c0)]) = pkw;
    }

    // ---- Q fragments direct from global ----
    const int arow = wv * 16 + jl;
    const int kq0  = hi << 3;
    const float* qr = Qp + arow * 64 + kq0;
    const f32x4 qa = *reinterpret_cast<const f32x4*>(qr);
    const f32x4 qb = *reinterpret_cast<const f32x4*>(qr + 4);
    const f32x4 qc = *reinterpret_cast<const f32x4*>(qr + 32);
    const f32x4 qd = *reinterpret_cast<const f32x4*>(qr + 36);
    bf16x8 aq0, aq1;
    #pragma unroll
    for (int q = 0; q < 4; ++q) {
        aq0[q]     = (short)bfb(qa[q] * scale);
        aq0[q + 4] = (short)bfb(qb[q] * scale);
        aq1[q]     = (short)bfb(qc[q] * scale);
        aq1[q + 4] = (short)bfb(qd[q] * scale);
    }

    __syncthreads();  // B1: RW + V staged

    const int tMax = wv + 8;

    // ---- e-loop: emb slots (slot s = rel-tile s+7-wv), packed bf16 (r3-verified) ----
    unsigned int e01[17], e23[17];
    __builtin_amdgcn_s_setprio(1);
    #pragma unroll
    for (int s = 0; s < 17; ++s) {
        unsigned int p01 = 0, p23 = 0;
        const int ts = s + 7 - wv;
        if (ts >= 0 && ts < 16) {
            const int rr = ts * 16 + jl;
            const bf16x8 b0 = *reinterpret_cast<const bf16x8*>(&sB[swz64(rr, kq0)]);
            const bf16x8 b1 = *reinterpret_cast<const bf16x8*>(&sB[swz64(rr, 32 + kq0)]);
            f32x4 e = {0.f, 0.f, 0.f, 0.f};
            e = mfma16(aq0, b0, e);
            e = mfma16(aq1, b1, e);
            p01 = pk2(e[0], e[1]);
            p23 = pk2(e[2], e[3]);
        }
        e01[s] = p01; e23[s] = p23;
    }
    __builtin_amdgcn_s_setprio(0);

    __syncthreads();  // B2: RW reads done -> sB reusable

    // ---- kpk dump -> sB (short section) ----
    #pragma unroll
    for (int pp = 0; pp < 8; ++pp) {
        const int row = pp * 32 + cr;
        *reinterpret_cast<uint2*>(&sB[swz64(row, c0)]) = kpk[pp];
    }

    __syncthreads();  // B3: K_norm staged

    // ---- fused loop: per kt-step {QK + bias + masks + exp -> sP} then PV ----
    const int cv0 = 4 * hi + 1, cv1 = 4 * hi + 2, cv2 = 4 * hi + 3, cv3 = 4 * hi + 4;
    const int sl0 = (hi << 4) | ((jl - cv0) & 15);
    const int sl1 = (hi << 4) | ((jl - cv1) & 15);
    const int sl2 = (hi << 4) | ((jl - cv2) & 15);
    const int sl3 = (hi << 4) | ((jl - cv3) & 15);
    const bool g0 = jl >= cv0, g1 = jl >= cv1, g2 = jl >= cv2, g3 = jl >= cv3;

    unsigned int lo0 = (unsigned int)__shfl((int)e01[0], sl0);
    unsigned int lo1 = (unsigned int)__shfl((int)e01[0], sl1);
    unsigned int lo2 = (unsigned int)__shfl((int)e23[0], sl2);
    unsigned int lo3 = (unsigned int)__shfl((int)e23[0], sl3);

    float sm[4] = {0.f, 0.f, 0.f, 0.f};
    const bool npad = (n == 0);
    f32x4 o[4] = {};

    #pragma unroll
    for (int pv = 0; pv < 8; ++pv) {
        if (2 * pv <= tMax) {
            #pragma unroll
            for (int tt = 0; tt < 2; ++tt) {
                const int t = 2 * pv + tt;
                unsigned int w01 = 0, w23 = 0;
                if (t <= tMax) {
                    // QK tile t
                    const int rr = t * 16 + jl;
                    const bf16x8 b0 = *reinterpret_cast<const bf16x8*>(&sB[swz64(rr, kq0)]);
                    const bf16x8 b1 = *reinterpret_cast<const bf16x8*>(&sB[swz64(rr, 32 + kq0)]);
                    f32x4 d = {0.f, 0.f, 0.f, 0.f};
                    d = mfma16(aq0, b0, d);
                    d = mfma16(aq1, b1, d);
                    // bias from e-slots t, t+1 (rolling)
                    const unsigned int h0 = (unsigned int)__shfl((int)e01[t + 1], sl0);
                    const unsigned int h1 = (unsigned int)__shfl((int)e01[t + 1], sl1);
                    const unsigned int h2 = (unsigned int)__shfl((int)e23[t + 1], sl2);
                    const unsigned int h3 = (unsigned int)__shfl((int)e23[t + 1], sl3);
                    d[0] += bf2f_lo(g0 ? h0 : lo0);
                    d[1] += bf2f_hi(g1 ? h1 : lo1);
                    d[2] += bf2f_lo(g2 ? h2 : lo2);
                    d[3] += bf2f_hi(g3 ? h3 : lo3);
                    lo0 = h0; lo1 = h1; lo2 = h2; lo3 = h3;
                    // masks
                    if (t >= 8 && t == tMax) {
                        #pragma unroll
                        for (int r = 0; r < 4; ++r) {
                            const int dd = 128 + jl - 4 * hi - r;
                            float x = d[r];
                            x = (dd == 128) ? -50.0f : x;   // self (exp=2e-22 keeps token-0 alive)
                            x = (dd > 128) ? -3.0e38f : x;  // causal
                            d[r] = x;
                        }
                    }
                    if (t < 8 && npad) {
                        #pragma unroll
                        for (int r = 0; r < 4; ++r) d[r] = -3.0e38f;
                    }
                    // exp + sum + pack
                    f32x4 pe;
                    #pragma unroll
                    for (int r = 0; r < 4; ++r) {
                        pe[r] = __expf(d[r]);
                        sm[r] += pe[r];
                    }
                    w01 = pk2(pe[0], pe[1]);
                    w23 = pk2(pe[2], pe[3]);
                }
                const int col = tt * 16 + jl;
                sP[pIdx(wv, 4 * hi + 0, col)] = (unsigned short)w01;
                sP[pIdx(wv, 4 * hi + 1, col)] = (unsigned short)(w01 >> 16);
                sP[pIdx(wv, 4 * hi + 2, col)] = (unsigned short)w23;
                sP[pIdx(wv, 4 * hi + 3, col)] = (unsigned short)(w23 >> 16);
            }
            // PV for this kt-step
            const bf16x8 pa = *reinterpret_cast<const bf16x8*>(&sP[pIdx(wv, jl, kq0)]);
            __builtin_amdgcn_s_setprio(1);
            #pragma unroll
            for (int ct = 0; ct < 4; ++ct) {
                const bf16x8 vb = *reinterpret_cast<const bf16x8*>(&sV[vIdx(ct * 16 + jl, pv * 32 + kq0)]);
                o[ct] = mfma16(pa, vb, o[ct]);
            }
            __builtin_amdgcn_s_setprio(0);
        }
    }

    // ---- epilogue: reduce sm, normalize, store ----
    float rinv[4];
    #pragma unroll
    for (int r = 0; r < 4; ++r) {
        sm[r] += __shfl_xor(sm[r], 1);
        sm[r] += __shfl_xor(sm[r], 2);
        sm[r] += __shfl_xor(sm[r], 4);
        sm[r] += __shfl_xor(sm[r], 8);
        rinv[r] = 1.0f / sm[r];
    }
    const int ibase = wv * 16 + (hi << 2);
    float* Op = outg + bhOff + (size_t)n * 128 * 64;
    #pragma unroll
    for (int ct = 0; ct < 4; ++ct)
        #pragma unroll
        for (int r = 0; r < 4; ++r)
            Op[(ibase + r) * 64 + ct * 16 + jl] = o[ct][r] * rinv[r];
}

extern "C" void kernel_launch(void* const* d_in, const int* in_sizes, int n_in,
                              void* d_out, int out_size, void* d_ws, size_t ws_size,
                              hipStream_t stream) {
    const float* q  = (const float*)d_in[0];
    const float* k  = (const float*)d_in[1];
    const float* v  = (const float*)d_in[2];
    const float* rw = (const float*)d_in[3];
    float* out = (float*)d_out;
    local_attn_kernel<<<dim3(1024), dim3(512), 0, stream>>>(q, k, v, rw, out);
}